// Round 20
// baseline (573.264 us; speedup 1.0000x reference)
//
#include <hip/hip_runtime.h>
#include <hip/hip_bf16.h>
#include <stdint.h>

// ---------------------------------------------------------------------------
// GroupedQueryAttention: hidden(B,S,4096) -> fused QKV proj -> RoPE -> causal
// GQA flash attention -> out proj.  B=2 S=2048 H=32 Hk=8 D=128.  bf16 MFMA.
// r19: r18 + optional K-split x2 on the QKV GEMM (tail elimination: 384
// blocks = 2 rounds @75% util -> 768 half-K blocks = 3 rounds @100% util),
// guarded host-side on ws_size (needs 217 MB; falls back to r18 path).
// ---------------------------------------------------------------------------

#define HIDDEN 4096
#define NH 32
#define NKV 8
#define HD 128
#define SLEN 2048
#define BATCH 2
#define QKVLD 6144  // fused QKV row stride (cols: Q 0..4095, K 4096..5119, V 5120..6143)

typedef __attribute__((ext_vector_type(8))) short bf16x8;
typedef __attribute__((ext_vector_type(4))) float f32x4;

__device__ __forceinline__ unsigned short f2bf(float f) {
  __hip_bfloat16 h = __float2bfloat16(f);
  return *reinterpret_cast<unsigned short*>(&h);
}
__device__ __forceinline__ float bf2f(unsigned short h) {
  union { uint32_t u; float f; } v; v.u = ((uint32_t)h) << 16;
  return v.f;
}
__device__ __forceinline__ void gload_lds16(const void* g, void* l) {
  __builtin_amdgcn_global_load_lds(
      (const __attribute__((address_space(1))) unsigned int*)g,
      (__attribute__((address_space(3))) unsigned int*)l, 16, 0, 0);
}

// ---------------------------------------------------------------------------
// fp32 -> bf16 converts.  cvt_all fuses hidden+wq+wk+wv; cvt_f32_bf16
// standalone for wo (dst region free only after the QKV GEMM consumed Wqkv).
// ---------------------------------------------------------------------------
__device__ __forceinline__ void cvt_body(const float* __restrict__ in,
                                         unsigned short* __restrict__ out, int rb) {
  size_t i = ((size_t)rb * 256 + threadIdx.x) * 8;
  f32x4 a = *(const f32x4*)&in[i];
  f32x4 b = *(const f32x4*)&in[i + 4];
  bf16x8 o;
#pragma unroll
  for (int j = 0; j < 4; ++j) { o[j] = (short)f2bf(a[j]); o[4 + j] = (short)f2bf(b[j]); }
  *(bf16x8*)&out[i] = o;
}

__global__ __launch_bounds__(256) void cvt_f32_bf16(const float* __restrict__ in,
                                                    unsigned short* __restrict__ out) {
  cvt_body(in, out, blockIdx.x);
}

// grid 20480: [0,8192) hidden->Xbf, [8192,16384) wq, [16384,18432) wk,
// [18432,20480) wv -> packed Wqkv.
__global__ __launch_bounds__(256) void cvt_all(const float* __restrict__ h,
                                               const float* __restrict__ wq,
                                               const float* __restrict__ wk,
                                               const float* __restrict__ wv,
                                               unsigned short* __restrict__ Xbf,
                                               unsigned short* __restrict__ Wqkv) {
  int bid = blockIdx.x;
  if (bid < 8192) {
    cvt_body(h, Xbf, bid);
  } else if (bid < 16384) {
    cvt_body(wq, Wqkv, bid - 8192);
  } else if (bid < 18432) {
    cvt_body(wk, Wqkv + (size_t)4096 * 4096, bid - 16384);
  } else {
    cvt_body(wv, Wqkv + (size_t)5120 * 4096, bid - 18432);
  }
}

// bf16 partial add: out[i] = bf16(out[i] + p1[i]), 8 elems/thread, in place.
__global__ __launch_bounds__(256) void add_split(unsigned short* __restrict__ out,
                                                 const unsigned short* __restrict__ p1) {
  size_t i = ((size_t)blockIdx.x * 256 + threadIdx.x) * 8;
  bf16x8 a = *(const bf16x8*)&out[i];
  bf16x8 b = *(const bf16x8*)&p1[i];
  bf16x8 o;
#pragma unroll
  for (int j = 0; j < 8; ++j)
    o[j] = (short)f2bf(bf2f((unsigned short)a[j]) + bf2f((unsigned short)b[j]));
  *(bf16x8*)&out[i] = o;
}

// ---------------------------------------------------------------------------
// GEMM  C(M,N) = A(M,Kstride) @ B(N,Kstride)^T over K-range
// [blockIdx.y*Kloop, (blockIdx.y+1)*Kloop), bf16 in, OutT out to
// (blockIdx.y ? C1 : C0).  r12 schedule (best measured): cross-tile register
// double-buffer; 256x256 tile, BK=32, 8 waves (2x4 -> 128x64), 512 threads,
// 4 LDS buffers (4 x 32KB).  Per iteration:
//   stage(t+3) | vmcnt(8) | barrier | READ12(t+1)->regs[nxt] |
//   MFMA32(regs[cur]) | lgkmcnt(0)
// launch_bounds(512,2): do NOT tighten (r13: (512,4) capped VGPR at 64 and
// spilled acc to scratch, 10x regression).
// Swizzle (verified r5, conflicts=0): source chunk cc^((row>>1)&3), read
// slot lg^((lr>>1)&3).  M,N mult 256; Kloop mult 64 (NT even); grid.x%8==0.
// ---------------------------------------------------------------------------
__device__ __forceinline__ void store_out(unsigned short* C, size_t i, float v) { C[i] = f2bf(v); }
__device__ __forceinline__ void store_out(float* C, size_t i, float v) { C[i] = v; }

template <typename OutT>
__global__ __launch_bounds__(512, 2)
void gemm_bt256(const unsigned short* __restrict__ A, const unsigned short* __restrict__ B,
                OutT* __restrict__ C0, OutT* __restrict__ C1, int M, int N, int Kstride,
                int Kloop) {
  __shared__ __align__(16) unsigned short lds[4 * 2048 * 8];  // 4 x 32KB buffers

  const int tid = threadIdx.x;
  const int lane = tid & 63, w = tid >> 6;
  const int lr = lane & 15, lg = lane >> 4;
  const int wr = w >> 2, wc = w & 3;  // 2 x 4 wave grid
  const int rsw = (lr >> 1) & 3;

  const int koff = blockIdx.y * Kloop;
  OutT* C = blockIdx.y ? C1 : C0;

  const int nbn = N >> 8;
  const int nwg = gridDim.x;
  int wg = (int)blockIdx.x;
  wg = (wg & 7) * (nwg >> 3) + (wg >> 3);  // XCD-aware swizzle (grid.x%8==0)
  const int bm = wg / nbn, bn = wg % nbn;

  const unsigned short* Ab = A + (size_t)bm * 256 * Kstride + koff;
  const unsigned short* Bb = B + (size_t)bn * 256 * Kstride + koff;

  // stage source pointers: constant per thread (swizzled col-chunk), K-mul hoisted
  const int r0 = tid >> 2, s0 = (tid & 3) ^ ((tid >> 3) & 3);
  const int L1 = tid + 512;
  const int r1 = L1 >> 2, s1 = (L1 & 3) ^ ((L1 >> 3) & 3);
  const unsigned short* gA0 = Ab + (size_t)r0 * Kstride + s0 * 8;
  const unsigned short* gA1 = Ab + (size_t)r1 * Kstride + s1 * 8;
  const unsigned short* gB0 = Bb + (size_t)r0 * Kstride + s0 * 8;
  const unsigned short* gB1 = Bb + (size_t)r1 * Kstride + s1 * 8;

  // per-lane LDS read base (ushort units); buffer stride = 16384 ushort (32KB)
  const unsigned short* rdA = &lds[(size_t)(wr * 512 + lr * 4 + (lg ^ rsw)) * 8];
  const unsigned short* rdB = &lds[(size_t)(1024 + wc * 256 + lr * 4 + (lg ^ rsw)) * 8];

  f32x4 acc[8][4] = {};

  // stage one K-tile (A 16KB + B 16KB) into buf[t&3]; LDS dest linear,
  // global source column-chunk pre-swizzled.
  auto stage = [&](int t2) {
    unsigned short* lb = lds + (size_t)(t2 & 3) * 2048 * 8;
    const int off = t2 * 32;
    gload_lds16(gA0 + off, lb + (size_t)tid * 8);
    gload_lds16(gA1 + off, lb + (size_t)(512 + tid) * 8);
    gload_lds16(gB0 + off, lb + (size_t)(1024 + tid) * 8);
    gload_lds16(gB1 + off, lb + (size_t)(1536 + tid) * 8);
  };

#define READ12(af, bf, bsel)                                                      \
  {                                                                               \
    const unsigned short* pA_ = rdA + (size_t)(bsel)*16384;                       \
    const unsigned short* pB_ = rdB + (size_t)(bsel)*16384;                       \
    _Pragma("unroll") for (int mi_ = 0; mi_ < 8; ++mi_)                           \
        af[mi_] = *(const bf16x8*)(pA_ + mi_ * 512);                              \
    _Pragma("unroll") for (int ni_ = 0; ni_ < 4; ++ni_)                           \
        bf[ni_] = *(const bf16x8*)(pB_ + ni_ * 512);                              \
  }

#define MFMA32(af, bf)                                                            \
  __builtin_amdgcn_s_setprio(1);                                                  \
  _Pragma("unroll") for (int mi_ = 0; mi_ < 8; ++mi_)                             \
  _Pragma("unroll") for (int ni_ = 0; ni_ < 4; ++ni_)                             \
      acc[mi_][ni_] = __builtin_amdgcn_mfma_f32_16x16x32_bf16(                    \
          af[mi_], bf[ni_], acc[mi_][ni_], 0, 0, 0);                              \
  __builtin_amdgcn_s_setprio(0)

#define VMW(t)                                                                    \
  if ((t) + 3 < NT)      asm volatile("s_waitcnt vmcnt(8)" ::: "memory");         \
  else if ((t) + 2 < NT) asm volatile("s_waitcnt vmcnt(4)" ::: "memory");         \
  else if ((t) + 1 < NT) asm volatile("s_waitcnt vmcnt(0)" ::: "memory")

#define ITER(cur_a, cur_b, nxt_a, nxt_b, t)                                       \
  {                                                                               \
    if ((t) + 3 < NT) stage((t) + 3);                                             \
    VMW(t);                                                                       \
    __builtin_amdgcn_s_barrier();                                                 \
    if ((t) + 1 < NT) READ12(nxt_a, nxt_b, ((t) + 1) & 3);                        \
    MFMA32(cur_a, cur_b);                                                         \
    asm volatile("s_waitcnt lgkmcnt(0)" ::: "memory");                            \
  }

  const int NT = Kloop >> 5;  // Kloop multiple of 64 -> NT even

  bf16x8 afA[8], bfA[4], afB[8], bfB[4];

  // prologue: 3 tiles in flight; wait tile 0; load tile-0 fragments
  stage(0); stage(1); stage(2);
  asm volatile("s_waitcnt vmcnt(8)" ::: "memory");
  __builtin_amdgcn_s_barrier();
  READ12(afA, bfA, 0);

#pragma unroll 1
  for (int t = 0; t < NT; t += 2) {
    ITER(afA, bfA, afB, bfB, t);
    ITER(afB, bfB, afA, bfA, t + 1);
  }

#pragma unroll
  for (int mi = 0; mi < 8; ++mi)
#pragma unroll
    for (int ni = 0; ni < 4; ++ni)
#pragma unroll
      for (int r = 0; r < 4; ++r) {
        size_t row = (size_t)bm * 256 + wr * 128 + mi * 16 + lg * 4 + r;
        size_t col = (size_t)bn * 256 + wc * 64 + ni * 16 + lr;
        store_out(C, row * N + col, acc[mi][ni][r]);
      }
#undef READ12
#undef MFMA32
#undef VMW
#undef ITER
}

// ---------------------------------------------------------------------------
// RoPE tables + fused apply (Q and K in one launch; grid 5120)
// ---------------------------------------------------------------------------
__global__ __launch_bounds__(256) void rope_tables(float* __restrict__ ct, float* __restrict__ st) {
  int idx = blockIdx.x * 256 + threadIdx.x;  // S*64
  int s = idx >> 6, j = idx & 63;
  float inv = exp2f(-(float)j * (13.287712379549449f / 64.f));
  float f = (float)s * inv;
  ct[idx] = cosf(f);
  st[idx] = sinf(f);
}

__device__ __forceinline__ void rope_body(unsigned short* __restrict__ X, int ld,
                                          const float* __restrict__ ct,
                                          const float* __restrict__ st, int heads, int idx) {
  int jc = (idx & 7) * 8;
  int t2 = idx >> 3;
  int hh = t2 % heads;
  int row = t2 / heads;
  int s = row & (SLEN - 1);
  unsigned short* p = X + (size_t)row * ld + hh * HD;
  bf16x8 lo = *(bf16x8*)&p[jc];
  bf16x8 hi = *(bf16x8*)&p[64 + jc];
  bf16x8 nlo, nhi;
#pragma unroll
  for (int j = 0; j < 8; ++j) {
    float c = ct[s * 64 + jc + j];
    float sn = st[s * 64 + jc + j];
    float xl = bf2f((unsigned short)(lo[j]));
    float xh = bf2f((unsigned short)(hi[j]));
    nlo[j] = (short)f2bf(xl * c - xh * sn);
    nhi[j] = (short)f2bf(xh * c + xl * sn);
  }
  *(bf16x8*)&p[jc] = nlo;
  *(bf16x8*)&p[64 + jc] = nhi;
}

// grid 5120: [0,4096) -> Q (32 heads), [4096,5120) -> K (8 heads)
__global__ __launch_bounds__(256) void rope_apply_qk(unsigned short* __restrict__ QKV,
                                                     const float* __restrict__ ct,
                                                     const float* __restrict__ st) {
  int bid = blockIdx.x;
  if (bid < 4096) {
    rope_body(QKV, QKVLD, ct, st, NH, bid * 256 + threadIdx.x);
  } else {
    rope_body(QKV + 4096, QKVLD, ct, st, NKV, (bid - 4096) * 256 + threadIdx.x);
  }
}

// ---------------------------------------------------------------------------
// V (rows B*S at stride ld, 1024 cols) -> VT (B, NKV, HD, S)
// ---------------------------------------------------------------------------
__global__ __launch_bounds__(256) void transpose_v(const unsigned short* __restrict__ Vsrc, int ld,
                                                   unsigned short* __restrict__ VT) {
  __shared__ unsigned short tile[64][66];
  const int t = threadIdx.x;
  const int bs = blockIdx.x;
  const int bd = blockIdx.y;
  const int b = bs >> 5;
  const int s0 = (bs & 31) * 64;
  const int d0 = bd * 64;
#pragma unroll
  for (int it = 0; it < 2; ++it) {
    int si = (t >> 3) + it * 32;
    int dj = (t & 7) * 8;
    bf16x8 v = *(const bf16x8*)&Vsrc[(size_t)(b * SLEN + s0 + si) * ld + d0 + dj];
#pragma unroll
    for (int j = 0; j < 8; ++j) tile[si][dj + j] = (unsigned short)(v[j]);
  }
  __syncthreads();
#pragma unroll
  for (int it = 0; it < 2; ++it) {
    int di = (t >> 3) + it * 32;
    int sj = (t & 7) * 8;
    bf16x8 o;
#pragma unroll
    for (int j = 0; j < 8; ++j) o[j] = (short)tile[sj + j][di];
    int c = d0 + di;
    int kvh = c >> 7, d = c & 127;
    *(bf16x8*)&VT[(((size_t)b * NKV + kvh) * HD + d) * SLEN + s0 + sj] = o;
  }
}

// ---------------------------------------------------------------------------
// Flash attention (round-3 version, validated).
// ---------------------------------------------------------------------------
__global__ __launch_bounds__(256, 2)
void attn_fwd(const unsigned short* __restrict__ QKV, const unsigned short* __restrict__ VTm,
              unsigned short* __restrict__ Om) {
  const int blk = blockIdx.x;            // 0..511
  const int xcd = blk & 7, jj = blk >> 3;
  const int g = xcd + ((jj >> 5) << 3);  // (b,kvh) group 0..15, pinned per XCD
  const int pair = jj & 31;
  const int kvh = g & 7, b = g >> 3;
  const int tid = threadIdx.x;
  const int lane = tid & 63, w = tid >> 6;
  const int lr = lane & 15, lg = lane >> 4;
  const int h = kvh * 4 + w;

  __shared__ __align__(16) unsigned short Ksm[64 * 136];   // [key][d], pad +8
  __shared__ __align__(16) unsigned short Vsm[128 * 72];   // [d][key], pad +8
  __shared__ __align__(16) unsigned short Psm[4][32 * 72]; // per-wave [q][key], pad +8
  __shared__ float Alds[4][32];

  const float SL2E = 0.1275378504229740f;  // (1/sqrt(128)) * log2(e)

  const unsigned short* Kb0 = QKV + (size_t)(b * SLEN) * QKVLD + 4096 + kvh * HD;
  const unsigned short* VTb = VTm + ((size_t)(b * NKV + kvh) * HD) * SLEN;

#pragma unroll 1
  for (int halfq = 0; halfq < 2; ++halfq) {
    const int qt = halfq ? (63 - pair) : pair;
    const int q0 = qt * 32;
    const int ntiles = (qt >> 1) + 1;

    // Q fragments: q = ni*16+lr, d = kd*32+lg*8
    bf16x8 qf[2][4];
    const unsigned short* Qb = QKV + (size_t)(b * SLEN + q0) * QKVLD + h * HD;
#pragma unroll
    for (int ni = 0; ni < 2; ++ni)
#pragma unroll
      for (int kd = 0; kd < 4; ++kd)
        qf[ni][kd] = *(const bf16x8*)&Qb[(size_t)(ni * 16 + lr) * QKVLD + kd * 32 + lg * 8];

    f32x4 acc_o[2][8] = {};
    float m_run[2] = {-1e30f, -1e30f};
    float l_run[2] = {0.f, 0.f};

    // prefetch tile 0 -> regs
    bf16x8 kreg[4], vreg[4];
#pragma unroll
    for (int i = 0; i < 4; ++i) {
      int c = tid + i * 256;
      kreg[i] = *(const bf16x8*)&Kb0[(size_t)(c >> 4) * QKVLD + (c & 15) * 8];
      vreg[i] = *(const bf16x8*)&VTb[(size_t)(c >> 3) * SLEN + (c & 7) * 8];
    }

#pragma unroll 1
    for (int t = 0; t < ntiles; ++t) {
      const int kv0 = t * 64;
      __syncthreads();
#pragma unroll
      for (int i = 0; i < 4; ++i) {
        int c = tid + i * 256;
        *(bf16x8*)&Ksm[(c >> 4) * 136 + (c & 15) * 8] = kreg[i];
        *(bf16x8*)&Vsm[(c >> 3) * 72 + (c & 7) * 8] = vreg[i];
      }
      __syncthreads();

      if (t + 1 < ntiles) {
#pragma unroll
        for (int i = 0; i < 4; ++i) {
          int c = tid + i * 256;
          kreg[i] = *(const bf16x8*)&Kb0[(size_t)(kv0 + 64 + (c >> 4)) * QKVLD + (c & 15) * 8];
          vreg[i] = *(const bf16x8*)&VTb[(size_t)(c >> 3) * SLEN + kv0 + 64 + (c & 7) * 8];
        }
      }

      // QK^T: S^T(64 key x 32 q) = K @ Q^T
      f32x4 accs[4][2] = {};
#pragma unroll
      for (int kd = 0; kd < 4; ++kd) {
        bf16x8 kf[4];
#pragma unroll
        for (int mi = 0; mi < 4; ++mi)
          kf[mi] = *(const bf16x8*)&Ksm[(mi * 16 + lr) * 136 + kd * 32 + lg * 8];
        __builtin_amdgcn_s_setprio(1);
#pragma unroll
        for (int mi = 0; mi < 4; ++mi)
#pragma unroll
          for (int ni = 0; ni < 2; ++ni)
            accs[mi][ni] =
                __builtin_amdgcn_mfma_f32_16x16x32_bf16(kf[mi], qf[ni][kd], accs[mi][ni], 0, 0, 0);
        __builtin_amdgcn_s_setprio(0);
      }

      // online softmax, log2*scale domain
      const bool domask = (t == ntiles - 1);
      float alpha[2];
#pragma unroll
      for (int ni = 0; ni < 2; ++ni) {
        float cmax = -1e30f;
#pragma unroll
        for (int mi = 0; mi < 4; ++mi)
#pragma unroll
          for (int r = 0; r < 4; ++r) {
            float s = accs[mi][ni][r] * SL2E;
            if (domask) {
              int key = kv0 + mi * 16 + lg * 4 + r;
              int qq = q0 + ni * 16 + lr;
              if (key > qq) s = -1e30f;
            }
            accs[mi][ni][r] = s;
            cmax = fmaxf(cmax, s);
          }
        cmax = fmaxf(cmax, __shfl_xor(cmax, 16));
        cmax = fmaxf(cmax, __shfl_xor(cmax, 32));
        float mnew = fmaxf(m_run[ni], cmax);
        alpha[ni] = exp2f(m_run[ni] - mnew);
        float psum = 0.f;
#pragma unroll
        for (int mi = 0; mi < 4; ++mi)
#pragma unroll
          for (int r = 0; r < 4; ++r) {
            float p = exp2f(accs[mi][ni][r] - mnew);
            accs[mi][ni][r] = p;
            psum += p;
          }
        psum += __shfl_xor(psum, 16);
        psum += __shfl_xor(psum, 32);
        l_run[ni] = l_run[ni] * alpha[ni] + psum;
        m_run[ni] = mnew;
      }

      // exact defer-rescale: skip when running max unchanged (alpha==1)
      if (__any(alpha[0] < 1.f) || __any(alpha[1] < 1.f)) {
        if (lg == 0) { Alds[w][lr] = alpha[0]; Alds[w][16 + lr] = alpha[1]; }
        f32x4 al0 = *(const f32x4*)&Alds[w][lg * 4];
        f32x4 al1 = *(const f32x4*)&Alds[w][16 + lg * 4];
#pragma unroll
        for (int nd = 0; nd < 8; ++nd)
#pragma unroll
          for (int r = 0; r < 4; ++r) {
            acc_o[0][nd][r] *= al0[r];
            acc_o[1][nd][r] *= al1[r];
          }
      }

      // P (S^T: row=key, col=q) -> Psm[q][key] bf16
#pragma unroll
      for (int ni = 0; ni < 2; ++ni)
#pragma unroll
        for (int mi = 0; mi < 4; ++mi)
#pragma unroll
          for (int rp = 0; rp < 4; rp += 2) {
            uint32_t pk = (uint32_t)f2bf(accs[mi][ni][rp]) |
                          ((uint32_t)f2bf(accs[mi][ni][rp + 1]) << 16);
            *(uint32_t*)&Psm[w][(ni * 16 + lr) * 72 + mi * 16 + lg * 4 + rp] = pk;
          }

      // PV: O(32q x 128d) += P(32x64) @ V(64x128)
#pragma unroll
      for (int ks = 0; ks < 2; ++ks) {
        bf16x8 pa[2];
#pragma unroll
        for (int pm = 0; pm < 2; ++pm)
          pa[pm] = *(const bf16x8*)&Psm[w][(pm * 16 + lr) * 72 + ks * 32 + lg * 8];
        __builtin_amdgcn_s_setprio(1);
#pragma unroll
        for (int nd = 0; nd < 8; ++nd) {
          bf16x8 vb = *(const bf16x8*)&Vsm[(nd * 16 + lr) * 72 + ks * 32 + lg * 8];
#pragma unroll
          for (int pm = 0; pm < 2; ++pm)
            acc_o[pm][nd] =
                __builtin_amdgcn_mfma_f32_16x16x32_bf16(pa[pm], vb, acc_o[pm][nd], 0, 0, 0);
        }
        __builtin_amdgcn_s_setprio(0);
      }
    }

    // epilogue: O /= l, store bf16 at (b, q, h, d)
    if (lg == 0) {
      Alds[w][lr] = 1.f / l_run[0];
      Alds[w][16 + lr] = 1.f / l_run[1];
    }
    f32x4 li0 = *(const f32x4*)&Alds[w][lg * 4];
    f32x4 li1 = *(const f32x4*)&Alds[w][16 + lg * 4];
    unsigned short* Ob = Om + ((size_t)(b * SLEN + q0) * NH + h) * HD;
#pragma unroll
    for (int pm = 0; pm < 2; ++pm)
#pragma unroll
      for (int nd = 0; nd < 8; ++nd)
#pragma unroll
        for (int r = 0; r < 4; ++r) {
          int qq = pm * 16 + lg * 4 + r;
          float v = acc_o[pm][nd][r] * (pm ? li1[r] : li0[r]);
          Ob[(size_t)qq * (NH * HD) + nd * 16 + lr] = f2bf(v);
        }
  }
}

// ---------------------------------------------------------------------------
// Launcher.  d_in: hidden, attention_mask(unused: known causal), wq, wk, wv, wo
// Workspace: Xbf 32 | Wqkv 48 | QKV 48 | Ob 32 | VTb 8 | ct/st 1 = 169 MB;
// optional P1 partial (48 MB @169) if ws_size >= 217 MB (K-split path).
// ---------------------------------------------------------------------------
extern "C" void kernel_launch(void* const* d_in, const int* in_sizes, int n_in,
                              void* d_out, int out_size, void* d_ws, size_t ws_size,
                              hipStream_t stream) {
  const float* hidden = (const float*)d_in[0];
  const float* wq = (const float*)d_in[2];
  const float* wk = (const float*)d_in[3];
  const float* wv = (const float*)d_in[4];
  const float* wo = (const float*)d_in[5];

  char* ws = (char*)d_ws;
  const size_t MB = 1ull << 20;
  unsigned short* Xbf  = (unsigned short*)(ws);             // 32 MB (B*S,4096)
  unsigned short* Wqkv = (unsigned short*)(ws + 32 * MB);   // 48 MB (6144,4096) packed W
  unsigned short* QKV  = (unsigned short*)(ws + 80 * MB);   // 48 MB (B*S,6144)
  unsigned short* Ob   = (unsigned short*)(ws + 128 * MB);  // 32 MB (B*S,4096)
  unsigned short* VTb  = (unsigned short*)(ws + 160 * MB);  // 8 MB (B,8,128,S)
  float* ct = (float*)(ws + 168 * MB);                      // 0.5 MB
  float* st = (float*)(ws + 168 * MB + 524288);             // 0.5 MB
  unsigned short* P1   = (unsigned short*)(ws + 169 * MB);  // 48 MB (K-split partial)

  const bool ksplit = (ws_size >= 217 * MB);  // host-side, graph-safe

  // 1) bf16 casts, fused (hidden -> Xbf; wq/wk/wv -> packed Wqkv)
  cvt_all<<<20480, 256, 0, stream>>>(hidden, wq, wk, wv, Xbf, Wqkv);

  // 2) fused QKV projection: (4096,4096) @ (6144,4096)^T -> (4096,6144)
  if (ksplit) {
    // 768 half-K blocks = 3 full dispatch rounds (no 75%-util tail),
    // partials: y=0 -> QKV, y=1 -> P1; then add in place.
    gemm_bt256<unsigned short><<<dim3(384, 2), 512, 0, stream>>>(
        Xbf, Wqkv, QKV, P1, 4096, 6144, 4096, 2048);
    add_split<<<12288, 256, 0, stream>>>(QKV, P1);
  } else {
    gemm_bt256<unsigned short><<<dim3(384, 1), 512, 0, stream>>>(
        Xbf, Wqkv, QKV, QKV, 4096, 6144, 4096, 4096);
  }

  // 3) RoPE on Q and K columns of fused buffer (single launch)
  rope_tables<<<512, 256, 0, stream>>>(ct, st);
  rope_apply_qk<<<5120, 256, 0, stream>>>(QKV, ct, st);

  // 4) V -> V^T
  transpose_v<<<dim3(64, 16), 256, 0, stream>>>(QKV + 5120, QKVLD, VTb);

  // 5) causal GQA flash attention (paired q-tiles, XCD-grouped)
  attn_fwd<<<512, 256, 0, stream>>>(QKV, VTb, Ob);

  // 6) output projection (fp32 out, grid 256 = exactly 1 block/CU: no split)
  cvt_f32_bf16<<<8192, 256, 0, stream>>>(wo, Wqkv);
  gemm_bt256<float><<<dim3(256, 1), 512, 0, stream>>>(
      Ob, Wqkv, (float*)d_out, (float*)d_out, 4096, 4096, 4096, 4096);
}

// Round 21
// 562.032 us; speedup vs baseline: 1.0200x; 1.0200x over previous
//
#include <hip/hip_runtime.h>
#include <hip/hip_bf16.h>
#include <stdint.h>

// ---------------------------------------------------------------------------
// GroupedQueryAttention: hidden(B,S,4096) -> fused QKV proj -> RoPE -> causal
// GQA flash attention -> out proj.  B=2 S=2048 H=32 Hk=8 D=128.  bf16 MFMA.
// FINAL (r21 = r18, best measured 563 us): r12 GEMM (cross-tile register
// double-buffer, 231us QKV @38.7% MfmaUtil, 0 bank conflicts, no spills) +
// fused cvt_all + fused rope_apply_qk.  r19/r20's K-split reverted (measured
// wash: -20us GEMM +25us add pass).
// ---------------------------------------------------------------------------

#define HIDDEN 4096
#define NH 32
#define NKV 8
#define HD 128
#define SLEN 2048
#define BATCH 2
#define QKVLD 6144  // fused QKV row stride (cols: Q 0..4095, K 4096..5119, V 5120..6143)

typedef __attribute__((ext_vector_type(8))) short bf16x8;
typedef __attribute__((ext_vector_type(4))) float f32x4;

__device__ __forceinline__ unsigned short f2bf(float f) {
  __hip_bfloat16 h = __float2bfloat16(f);
  return *reinterpret_cast<unsigned short*>(&h);
}
__device__ __forceinline__ float bf2f(unsigned short h) {
  union { uint32_t u; float f; } v; v.u = ((uint32_t)h) << 16;
  return v.f;
}
__device__ __forceinline__ void gload_lds16(const void* g, void* l) {
  __builtin_amdgcn_global_load_lds(
      (const __attribute__((address_space(1))) unsigned int*)g,
      (__attribute__((address_space(3))) unsigned int*)l, 16, 0, 0);
}

// ---------------------------------------------------------------------------
// fp32 -> bf16 converts.  cvt_all fuses hidden+wq+wk+wv (one launch, region
// decode); cvt_f32_bf16 standalone for wo (dst region free only after the
// QKV GEMM consumed Wqkv).  Both at ~95% of achievable HBM BW.
// ---------------------------------------------------------------------------
__device__ __forceinline__ void cvt_body(const float* __restrict__ in,
                                         unsigned short* __restrict__ out, int rb) {
  size_t i = ((size_t)rb * 256 + threadIdx.x) * 8;
  f32x4 a = *(const f32x4*)&in[i];
  f32x4 b = *(const f32x4*)&in[i + 4];
  bf16x8 o;
#pragma unroll
  for (int j = 0; j < 4; ++j) { o[j] = (short)f2bf(a[j]); o[4 + j] = (short)f2bf(b[j]); }
  *(bf16x8*)&out[i] = o;
}

__global__ __launch_bounds__(256) void cvt_f32_bf16(const float* __restrict__ in,
                                                    unsigned short* __restrict__ out) {
  cvt_body(in, out, blockIdx.x);
}

// grid 20480: [0,8192) hidden->Xbf, [8192,16384) wq, [16384,18432) wk,
// [18432,20480) wv -> packed Wqkv.
__global__ __launch_bounds__(256) void cvt_all(const float* __restrict__ h,
                                               const float* __restrict__ wq,
                                               const float* __restrict__ wk,
                                               const float* __restrict__ wv,
                                               unsigned short* __restrict__ Xbf,
                                               unsigned short* __restrict__ Wqkv) {
  int bid = blockIdx.x;
  if (bid < 8192) {
    cvt_body(h, Xbf, bid);
  } else if (bid < 16384) {
    cvt_body(wq, Wqkv, bid - 8192);
  } else if (bid < 18432) {
    cvt_body(wk, Wqkv + (size_t)4096 * 4096, bid - 16384);
  } else {
    cvt_body(wv, Wqkv + (size_t)5120 * 4096, bid - 18432);
  }
}

// ---------------------------------------------------------------------------
// GEMM  C(M,N) = A(M,K) @ B(N,K)^T, bf16 in, OutT out.  (r12 — best measured)
// Cross-tile register double-buffer; 256x256 tile, BK=32, 8 waves (2x4 ->
// 128x64 each), 512 threads, 4 LDS buffers (4 x 32KB).  Per iteration:
//   stage(t+3) | vmcnt(8) | barrier | READ12(t+1)->regs[nxt] |
//   MFMA32(regs[cur]) | lgkmcnt(0)
// DS pipe drains next tile's reads while matrix pipe runs current tile.
// launch_bounds(512,2): do NOT tighten (r13: (512,4) capped VGPR at 64 and
// spilled acc to scratch, 10x regression).
// Swizzle (verified r5, conflicts=0): source chunk cc^((row>>1)&3), read
// slot lg^((lr>>1)&3).  M,N mult of 256; K mult of 64 (NT even); grid%8==0.
// ---------------------------------------------------------------------------
__device__ __forceinline__ void store_out(unsigned short* C, size_t i, float v) { C[i] = f2bf(v); }
__device__ __forceinline__ void store_out(float* C, size_t i, float v) { C[i] = v; }

template <typename OutT>
__global__ __launch_bounds__(512, 2)
void gemm_bt256(const unsigned short* __restrict__ A, const unsigned short* __restrict__ B,
                OutT* __restrict__ C, int M, int N, int K) {
  __shared__ __align__(16) unsigned short lds[4 * 2048 * 8];  // 4 x 32KB buffers

  const int tid = threadIdx.x;
  const int lane = tid & 63, w = tid >> 6;
  const int lr = lane & 15, lg = lane >> 4;
  const int wr = w >> 2, wc = w & 3;  // 2 x 4 wave grid
  const int rsw = (lr >> 1) & 3;

  const int nbn = N >> 8;
  const int nwg = gridDim.x;
  int wg = (int)blockIdx.x;
  wg = (wg & 7) * (nwg >> 3) + (wg >> 3);  // XCD-aware swizzle (nwg%8==0)
  const int bm = wg / nbn, bn = wg % nbn;

  const unsigned short* Ab = A + (size_t)bm * 256 * K;
  const unsigned short* Bb = B + (size_t)bn * 256 * K;

  // stage source pointers: constant per thread (swizzled col-chunk), K-mul hoisted
  const int r0 = tid >> 2, s0 = (tid & 3) ^ ((tid >> 3) & 3);
  const int L1 = tid + 512;
  const int r1 = L1 >> 2, s1 = (L1 & 3) ^ ((L1 >> 3) & 3);
  const unsigned short* gA0 = Ab + (size_t)r0 * K + s0 * 8;
  const unsigned short* gA1 = Ab + (size_t)r1 * K + s1 * 8;
  const unsigned short* gB0 = Bb + (size_t)r0 * K + s0 * 8;
  const unsigned short* gB1 = Bb + (size_t)r1 * K + s1 * 8;

  // per-lane LDS read base (ushort units); buffer stride = 16384 ushort (32KB)
  const unsigned short* rdA = &lds[(size_t)(wr * 512 + lr * 4 + (lg ^ rsw)) * 8];
  const unsigned short* rdB = &lds[(size_t)(1024 + wc * 256 + lr * 4 + (lg ^ rsw)) * 8];

  f32x4 acc[8][4] = {};

  // stage one K-tile (A 16KB + B 16KB) into buf[t&3]; LDS dest linear,
  // global source column-chunk pre-swizzled.
  auto stage = [&](int t2) {
    unsigned short* lb = lds + (size_t)(t2 & 3) * 2048 * 8;
    const int off = t2 * 32;
    gload_lds16(gA0 + off, lb + (size_t)tid * 8);
    gload_lds16(gA1 + off, lb + (size_t)(512 + tid) * 8);
    gload_lds16(gB0 + off, lb + (size_t)(1024 + tid) * 8);
    gload_lds16(gB1 + off, lb + (size_t)(1536 + tid) * 8);
  };

#define READ12(af, bf, bsel)                                                      \
  {                                                                               \
    const unsigned short* pA_ = rdA + (size_t)(bsel)*16384;                       \
    const unsigned short* pB_ = rdB + (size_t)(bsel)*16384;                       \
    _Pragma("unroll") for (int mi_ = 0; mi_ < 8; ++mi_)                           \
        af[mi_] = *(const bf16x8*)(pA_ + mi_ * 512);                              \
    _Pragma("unroll") for (int ni_ = 0; ni_ < 4; ++ni_)                           \
        bf[ni_] = *(const bf16x8*)(pB_ + ni_ * 512);                              \
  }

#define MFMA32(af, bf)                                                            \
  __builtin_amdgcn_s_setprio(1);                                                  \
  _Pragma("unroll") for (int mi_ = 0; mi_ < 8; ++mi_)                             \
  _Pragma("unroll") for (int ni_ = 0; ni_ < 4; ++ni_)                             \
      acc[mi_][ni_] = __builtin_amdgcn_mfma_f32_16x16x32_bf16(                    \
          af[mi_], bf[ni_], acc[mi_][ni_], 0, 0, 0);                              \
  __builtin_amdgcn_s_setprio(0)

#define VMW(t)                                                                    \
  if ((t) + 3 < NT)      asm volatile("s_waitcnt vmcnt(8)" ::: "memory");         \
  else if ((t) + 2 < NT) asm volatile("s_waitcnt vmcnt(4)" ::: "memory");         \
  else if ((t) + 1 < NT) asm volatile("s_waitcnt vmcnt(0)" ::: "memory")

#define ITER(cur_a, cur_b, nxt_a, nxt_b, t)                                       \
  {                                                                               \
    if ((t) + 3 < NT) stage((t) + 3);                                             \
    VMW(t);                                                                       \
    __builtin_amdgcn_s_barrier();                                                 \
    if ((t) + 1 < NT) READ12(nxt_a, nxt_b, ((t) + 1) & 3);                        \
    MFMA32(cur_a, cur_b);                                                         \
    asm volatile("s_waitcnt lgkmcnt(0)" ::: "memory");                            \
  }

  const int NT = K >> 5;  // K multiple of 64 -> NT even

  bf16x8 afA[8], bfA[4], afB[8], bfB[4];

  // prologue: 3 tiles in flight; wait tile 0; load tile-0 fragments
  stage(0); stage(1); stage(2);
  asm volatile("s_waitcnt vmcnt(8)" ::: "memory");
  __builtin_amdgcn_s_barrier();
  READ12(afA, bfA, 0);

#pragma unroll 1
  for (int t = 0; t < NT; t += 2) {
    ITER(afA, bfA, afB, bfB, t);
    ITER(afB, bfB, afA, bfA, t + 1);
  }

#pragma unroll
  for (int mi = 0; mi < 8; ++mi)
#pragma unroll
    for (int ni = 0; ni < 4; ++ni)
#pragma unroll
      for (int r = 0; r < 4; ++r) {
        size_t row = (size_t)bm * 256 + wr * 128 + mi * 16 + lg * 4 + r;
        size_t col = (size_t)bn * 256 + wc * 64 + ni * 16 + lr;
        store_out(C, row * N + col, acc[mi][ni][r]);
      }
#undef READ12
#undef MFMA32
#undef VMW
#undef ITER
}

// ---------------------------------------------------------------------------
// RoPE tables + fused apply (Q and K in one launch; grid 5120)
// ---------------------------------------------------------------------------
__global__ __launch_bounds__(256) void rope_tables(float* __restrict__ ct, float* __restrict__ st) {
  int idx = blockIdx.x * 256 + threadIdx.x;  // S*64
  int s = idx >> 6, j = idx & 63;
  float inv = exp2f(-(float)j * (13.287712379549449f / 64.f));
  float f = (float)s * inv;
  ct[idx] = cosf(f);
  st[idx] = sinf(f);
}

__device__ __forceinline__ void rope_body(unsigned short* __restrict__ X, int ld,
                                          const float* __restrict__ ct,
                                          const float* __restrict__ st, int heads, int idx) {
  int jc = (idx & 7) * 8;
  int t2 = idx >> 3;
  int hh = t2 % heads;
  int row = t2 / heads;
  int s = row & (SLEN - 1);
  unsigned short* p = X + (size_t)row * ld + hh * HD;
  bf16x8 lo = *(bf16x8*)&p[jc];
  bf16x8 hi = *(bf16x8*)&p[64 + jc];
  bf16x8 nlo, nhi;
#pragma unroll
  for (int j = 0; j < 8; ++j) {
    float c = ct[s * 64 + jc + j];
    float sn = st[s * 64 + jc + j];
    float xl = bf2f((unsigned short)(lo[j]));
    float xh = bf2f((unsigned short)(hi[j]));
    nlo[j] = (short)f2bf(xl * c - xh * sn);
    nhi[j] = (short)f2bf(xh * c + xl * sn);
  }
  *(bf16x8*)&p[jc] = nlo;
  *(bf16x8*)&p[64 + jc] = nhi;
}

// grid 5120: [0,4096) -> Q (32 heads), [4096,5120) -> K (8 heads)
__global__ __launch_bounds__(256) void rope_apply_qk(unsigned short* __restrict__ QKV,
                                                     const float* __restrict__ ct,
                                                     const float* __restrict__ st) {
  int bid = blockIdx.x;
  if (bid < 4096) {
    rope_body(QKV, QKVLD, ct, st, NH, bid * 256 + threadIdx.x);
  } else {
    rope_body(QKV + 4096, QKVLD, ct, st, NKV, (bid - 4096) * 256 + threadIdx.x);
  }
}

// ---------------------------------------------------------------------------
// V (rows B*S at stride ld, 1024 cols) -> VT (B, NKV, HD, S)
// ---------------------------------------------------------------------------
__global__ __launch_bounds__(256) void transpose_v(const unsigned short* __restrict__ Vsrc, int ld,
                                                   unsigned short* __restrict__ VT) {
  __shared__ unsigned short tile[64][66];
  const int t = threadIdx.x;
  const int bs = blockIdx.x;
  const int bd = blockIdx.y;
  const int b = bs >> 5;
  const int s0 = (bs & 31) * 64;
  const int d0 = bd * 64;
#pragma unroll
  for (int it = 0; it < 2; ++it) {
    int si = (t >> 3) + it * 32;
    int dj = (t & 7) * 8;
    bf16x8 v = *(const bf16x8*)&Vsrc[(size_t)(b * SLEN + s0 + si) * ld + d0 + dj];
#pragma unroll
    for (int j = 0; j < 8; ++j) tile[si][dj + j] = (unsigned short)(v[j]);
  }
  __syncthreads();
#pragma unroll
  for (int it = 0; it < 2; ++it) {
    int di = (t >> 3) + it * 32;
    int sj = (t & 7) * 8;
    bf16x8 o;
#pragma unroll
    for (int j = 0; j < 8; ++j) o[j] = (short)tile[sj + j][di];
    int c = d0 + di;
    int kvh = c >> 7, d = c & 127;
    *(bf16x8*)&VT[(((size_t)b * NKV + kvh) * HD + d) * SLEN + s0 + sj] = o;
  }
}

// ---------------------------------------------------------------------------
// Flash attention (round-3 version, validated).
// ---------------------------------------------------------------------------
__global__ __launch_bounds__(256, 2)
void attn_fwd(const unsigned short* __restrict__ QKV, const unsigned short* __restrict__ VTm,
              unsigned short* __restrict__ Om) {
  const int blk = blockIdx.x;            // 0..511
  const int xcd = blk & 7, jj = blk >> 3;
  const int g = xcd + ((jj >> 5) << 3);  // (b,kvh) group 0..15, pinned per XCD
  const int pair = jj & 31;
  const int kvh = g & 7, b = g >> 3;
  const int tid = threadIdx.x;
  const int lane = tid & 63, w = tid >> 6;
  const int lr = lane & 15, lg = lane >> 4;
  const int h = kvh * 4 + w;

  __shared__ __align__(16) unsigned short Ksm[64 * 136];   // [key][d], pad +8
  __shared__ __align__(16) unsigned short Vsm[128 * 72];   // [d][key], pad +8
  __shared__ __align__(16) unsigned short Psm[4][32 * 72]; // per-wave [q][key], pad +8
  __shared__ float Alds[4][32];

  const float SL2E = 0.1275378504229740f;  // (1/sqrt(128)) * log2(e)

  const unsigned short* Kb0 = QKV + (size_t)(b * SLEN) * QKVLD + 4096 + kvh * HD;
  const unsigned short* VTb = VTm + ((size_t)(b * NKV + kvh) * HD) * SLEN;

#pragma unroll 1
  for (int halfq = 0; halfq < 2; ++halfq) {
    const int qt = halfq ? (63 - pair) : pair;
    const int q0 = qt * 32;
    const int ntiles = (qt >> 1) + 1;

    // Q fragments: q = ni*16+lr, d = kd*32+lg*8
    bf16x8 qf[2][4];
    const unsigned short* Qb = QKV + (size_t)(b * SLEN + q0) * QKVLD + h * HD;
#pragma unroll
    for (int ni = 0; ni < 2; ++ni)
#pragma unroll
      for (int kd = 0; kd < 4; ++kd)
        qf[ni][kd] = *(const bf16x8*)&Qb[(size_t)(ni * 16 + lr) * QKVLD + kd * 32 + lg * 8];

    f32x4 acc_o[2][8] = {};
    float m_run[2] = {-1e30f, -1e30f};
    float l_run[2] = {0.f, 0.f};

    // prefetch tile 0 -> regs
    bf16x8 kreg[4], vreg[4];
#pragma unroll
    for (int i = 0; i < 4; ++i) {
      int c = tid + i * 256;
      kreg[i] = *(const bf16x8*)&Kb0[(size_t)(c >> 4) * QKVLD + (c & 15) * 8];
      vreg[i] = *(const bf16x8*)&VTb[(size_t)(c >> 3) * SLEN + (c & 7) * 8];
    }

#pragma unroll 1
    for (int t = 0; t < ntiles; ++t) {
      const int kv0 = t * 64;
      __syncthreads();
#pragma unroll
      for (int i = 0; i < 4; ++i) {
        int c = tid + i * 256;
        *(bf16x8*)&Ksm[(c >> 4) * 136 + (c & 15) * 8] = kreg[i];
        *(bf16x8*)&Vsm[(c >> 3) * 72 + (c & 7) * 8] = vreg[i];
      }
      __syncthreads();

      if (t + 1 < ntiles) {
#pragma unroll
        for (int i = 0; i < 4; ++i) {
          int c = tid + i * 256;
          kreg[i] = *(const bf16x8*)&Kb0[(size_t)(kv0 + 64 + (c >> 4)) * QKVLD + (c & 15) * 8];
          vreg[i] = *(const bf16x8*)&VTb[(size_t)(c >> 3) * SLEN + kv0 + 64 + (c & 7) * 8];
        }
      }

      // QK^T: S^T(64 key x 32 q) = K @ Q^T
      f32x4 accs[4][2] = {};
#pragma unroll
      for (int kd = 0; kd < 4; ++kd) {
        bf16x8 kf[4];
#pragma unroll
        for (int mi = 0; mi < 4; ++mi)
          kf[mi] = *(const bf16x8*)&Ksm[(mi * 16 + lr) * 136 + kd * 32 + lg * 8];
        __builtin_amdgcn_s_setprio(1);
#pragma unroll
        for (int mi = 0; mi < 4; ++mi)
#pragma unroll
          for (int ni = 0; ni < 2; ++ni)
            accs[mi][ni] =
                __builtin_amdgcn_mfma_f32_16x16x32_bf16(kf[mi], qf[ni][kd], accs[mi][ni], 0, 0, 0);
        __builtin_amdgcn_s_setprio(0);
      }

      // online softmax, log2*scale domain
      const bool domask = (t == ntiles - 1);
      float alpha[2];
#pragma unroll
      for (int ni = 0; ni < 2; ++ni) {
        float cmax = -1e30f;
#pragma unroll
        for (int mi = 0; mi < 4; ++mi)
#pragma unroll
          for (int r = 0; r < 4; ++r) {
            float s = accs[mi][ni][r] * SL2E;
            if (domask) {
              int key = kv0 + mi * 16 + lg * 4 + r;
              int qq = q0 + ni * 16 + lr;
              if (key > qq) s = -1e30f;
            }
            accs[mi][ni][r] = s;
            cmax = fmaxf(cmax, s);
          }
        cmax = fmaxf(cmax, __shfl_xor(cmax, 16));
        cmax = fmaxf(cmax, __shfl_xor(cmax, 32));
        float mnew = fmaxf(m_run[ni], cmax);
        alpha[ni] = exp2f(m_run[ni] - mnew);
        float psum = 0.f;
#pragma unroll
        for (int mi = 0; mi < 4; ++mi)
#pragma unroll
          for (int r = 0; r < 4; ++r) {
            float p = exp2f(accs[mi][ni][r] - mnew);
            accs[mi][ni][r] = p;
            psum += p;
          }
        psum += __shfl_xor(psum, 16);
        psum += __shfl_xor(psum, 32);
        l_run[ni] = l_run[ni] * alpha[ni] + psum;
        m_run[ni] = mnew;
      }

      // exact defer-rescale: skip when running max unchanged (alpha==1)
      if (__any(alpha[0] < 1.f) || __any(alpha[1] < 1.f)) {
        if (lg == 0) { Alds[w][lr] = alpha[0]; Alds[w][16 + lr] = alpha[1]; }
        f32x4 al0 = *(const f32x4*)&Alds[w][lg * 4];
        f32x4 al1 = *(const f32x4*)&Alds[w][16 + lg * 4];
#pragma unroll
        for (int nd = 0; nd < 8; ++nd)
#pragma unroll
          for (int r = 0; r < 4; ++r) {
            acc_o[0][nd][r] *= al0[r];
            acc_o[1][nd][r] *= al1[r];
          }
      }

      // P (S^T: row=key, col=q) -> Psm[q][key] bf16
#pragma unroll
      for (int ni = 0; ni < 2; ++ni)
#pragma unroll
        for (int mi = 0; mi < 4; ++mi)
#pragma unroll
          for (int rp = 0; rp < 4; rp += 2) {
            uint32_t pk = (uint32_t)f2bf(accs[mi][ni][rp]) |
                          ((uint32_t)f2bf(accs[mi][ni][rp + 1]) << 16);
            *(uint32_t*)&Psm[w][(ni * 16 + lr) * 72 + mi * 16 + lg * 4 + rp] = pk;
          }

      // PV: O(32q x 128d) += P(32x64) @ V(64x128)
#pragma unroll
      for (int ks = 0; ks < 2; ++ks) {
        bf16x8 pa[2];
#pragma unroll
        for (int pm = 0; pm < 2; ++pm)
          pa[pm] = *(const bf16x8*)&Psm[w][(pm * 16 + lr) * 72 + ks * 32 + lg * 8];
        __builtin_amdgcn_s_setprio(1);
#pragma unroll
        for (int nd = 0; nd < 8; ++nd) {
          bf16x8 vb = *(const bf16x8*)&Vsm[(nd * 16 + lr) * 72 + ks * 32 + lg * 8];
#pragma unroll
          for (int pm = 0; pm < 2; ++pm)
            acc_o[pm][nd] =
                __builtin_amdgcn_mfma_f32_16x16x32_bf16(pa[pm], vb, acc_o[pm][nd], 0, 0, 0);
        }
        __builtin_amdgcn_s_setprio(0);
      }
    }

    // epilogue: O /= l, store bf16 at (b, q, h, d)
    if (lg == 0) {
      Alds[w][lr] = 1.f / l_run[0];
      Alds[w][16 + lr] = 1.f / l_run[1];
    }
    f32x4 li0 = *(const f32x4*)&Alds[w][lg * 4];
    f32x4 li1 = *(const f32x4*)&Alds[w][16 + lg * 4];
    unsigned short* Ob = Om + ((size_t)(b * SLEN + q0) * NH + h) * HD;
#pragma unroll
    for (int pm = 0; pm < 2; ++pm)
#pragma unroll
      for (int nd = 0; nd < 8; ++nd)
#pragma unroll
        for (int r = 0; r < 4; ++r) {
          int qq = pm * 16 + lg * 4 + r;
          float v = acc_o[pm][nd][r] * (pm ? li1[r] : li0[r]);
          Ob[(size_t)qq * (NH * HD) + nd * 16 + lr] = f2bf(v);
        }
  }
}

// ---------------------------------------------------------------------------
// Launcher.  d_in: hidden, attention_mask(unused: known causal), wq, wk, wv, wo
// Workspace (169 MB): Xbf 32 | Wqkv 48 | QKV 48 | Ob 32 | VTb 8 | ct/st 1
// ---------------------------------------------------------------------------
extern "C" void kernel_launch(void* const* d_in, const int* in_sizes, int n_in,
                              void* d_out, int out_size, void* d_ws, size_t ws_size,
                              hipStream_t stream) {
  const float* hidden = (const float*)d_in[0];
  const float* wq = (const float*)d_in[2];
  const float* wk = (const float*)d_in[3];
  const float* wv = (const float*)d_in[4];
  const float* wo = (const float*)d_in[5];

  char* ws = (char*)d_ws;
  const size_t MB = 1ull << 20;
  unsigned short* Xbf  = (unsigned short*)(ws);             // 32 MB (B*S,4096)
  unsigned short* Wqkv = (unsigned short*)(ws + 32 * MB);   // 48 MB (6144,4096) packed W
  unsigned short* QKV  = (unsigned short*)(ws + 80 * MB);   // 48 MB (B*S,6144)
  unsigned short* Ob   = (unsigned short*)(ws + 128 * MB);  // 32 MB (B*S,4096)
  unsigned short* VTb  = (unsigned short*)(ws + 160 * MB);  // 8 MB (B,8,128,S)
  float* ct = (float*)(ws + 168 * MB);                      // 0.5 MB
  float* st = (float*)(ws + 168 * MB + 524288);             // 0.5 MB

  // 1) bf16 casts, fused (hidden -> Xbf; wq/wk/wv -> packed Wqkv)
  cvt_all<<<20480, 256, 0, stream>>>(hidden, wq, wk, wv, Xbf, Wqkv);

  // 2) fused QKV projection: (4096,4096) @ (6144,4096)^T -> (4096,6144)
  gemm_bt256<unsigned short><<<384, 512, 0, stream>>>(Xbf, Wqkv, QKV, 4096, 6144, 4096);

  // 3) RoPE on Q and K columns of fused buffer (single launch)
  rope_tables<<<512, 256, 0, stream>>>(ct, st);
  rope_apply_qk<<<5120, 256, 0, stream>>>(QKV, ct, st);

  // 4) V -> V^T
  transpose_v<<<dim3(64, 16), 256, 0, stream>>>(QKV + 5120, QKVLD, VTb);

  // 5) causal GQA flash attention (paired q-tiles, XCD-grouped)
  attn_fwd<<<512, 256, 0, stream>>>(QKV, VTb, Ob);

  // 6) output projection (fp32 out); Wqkv region reused for Wo
  cvt_f32_bf16<<<8192, 256, 0, stream>>>(wo, Wqkv);
  gemm_bt256<float><<<256, 512, 0, stream>>>(Ob, Wqkv, (float*)d_out, 4096, 4096, 4096);
}